// Round 19
// baseline (242.553 us; speedup 1.0000x reference)
//
#include <hip/hip_runtime.h>
#include <hip/hip_bf16.h>

// Round 19: middle-section pipelining. gmap and lmap merged with prev-transpose
//           work (block-range split, m114 inter-block MFMA/BW overlap), prevbf
//           split into 2-batch halves A/B (alias-audited). Bodies = r18.
// ws layout (62.12 MB):
//   [0, 37,748,736)           curbf bf16 [8][9216][256]        (K1..K6) -- later hcat8 [8][8][9604][32] (K7+)
//   [39,337,984, 48,775,168)  prevbfB (K3+; overlaps hcat1+fibf region, time-disjoint)
//   [39,337,984, 40,567,296)  hcat1 (K7+)
//   [40,567,296, 43,229,696)  fibf+si (K1..K2)
//   [48,775,168, 58,212,352)  prevbfA (K2+)
//   [40,567,296, 60,236,288)  hmid_pad (K8+)
//   [60,236,288, 60,908,032)  W1bf (slab 81 = zbuf)
//   [60,908,032, 60,944,896)  W2bf
//   [60,944,896, 61,534,720)  gout ; [61,534,720, 62,124,544) lout

typedef __hip_bfloat16 bf16;
typedef __attribute__((ext_vector_type(8))) short short8;
typedef __attribute__((ext_vector_type(4))) float f32x4;

constexpr int B_  = 8;
constexpr int C_  = 256;
constexpr int H_  = 96;
constexpr int W_  = 96;
constexpr int HW_ = H_ * W_;       // 9216
constexpr int PW_ = 24;
constexpr int KP_ = 576;
constexpr int KPP = 640;
constexpr int HP_ = 98;
constexpr int HPW = HP_ * HP_;     // 9604
constexpr int CHK = HPW * 32;

__device__ __forceinline__ unsigned short bfb(float f) {
    bf16 h = __float2bfloat16(f);
    return *reinterpret_cast<unsigned short*>(&h);
}

__device__ __forceinline__ void gload_lds16(const bf16* g, bf16* l) {
    __builtin_amdgcn_global_load_lds((const void*)g, (void*)l, 16, 0, 0);
}

// ------------------------------------------------------------ prep ----
// blocks [0,1384): W1/W2 convert ; [1384,6544): pool ; [6544,11152): tcur(cur).
__global__ __launch_bounds__(256)
void prep_kernel(const float* __restrict__ W1, const float* __restrict__ W2,
                 const float* __restrict__ init_embed, const float* __restrict__ init_seg,
                 const float* __restrict__ cur_embed,
                 bf16* __restrict__ w1bf, bf16* __restrict__ w2bf,
                 bf16* __restrict__ fibf, float* __restrict__ si,
                 bf16* __restrict__ curbf)
{
    __shared__ float tile[64][68];
    int gid = blockIdx.x;
    int t = threadIdx.x;
    if (gid < 1384) {
        int idx = gid * 256 + t;
        if (idx < 82 * 128 * 32) {
            int ic = idx & 31;
            int oc = (idx >> 5) & 127;
            int ks = idx >> 12;
            int icc = ks / 9, tap = ks % 9;
            int icg = icc * 32 + ic;
            float v = (icg < 264) ? W1[((size_t)oc * 264 + icg) * 9 + tap] : 0.f;
            w1bf[idx] = __float2bfloat16(v);
        } else {
            int j = idx - 82 * 128 * 32;
            if (j >= 18 * 16 * 64) return;
            int c  = j & 63;
            int oc = (j >> 6) & 15;
            int s  = j >> 10;
            int tap = s >> 1, half = s & 1;
            float v = (oc < 2) ? W2[((size_t)oc * 128 + half * 64 + c) * 9 + tap] : 0.f;
            w2bf[j] = __float2bfloat16(v);
        }
    } else if (gid < 6544) {
        int idx = (gid - 1384) * 256 + t;
        int k  = idx % KPP;
        int ch = (idx / KPP) % (C_ + 2);
        int b  = idx / (KPP * (C_ + 2));
        float s = 0.f;
        if (k < KP_) {
            int ph = k / PW_, pw = k % PW_;
            const float* src = (ch < C_)
                ? (init_embed + (((size_t)b * C_ + ch) * H_ + ph * 4) * W_ + pw * 4)
                : (init_seg   + (((size_t)b * 2 + (ch - C_)) * H_ + ph * 4) * W_ + pw * 4);
            #pragma unroll
            for (int r = 0; r < 4; r++) {
                float4 v = *reinterpret_cast<const float4*>(src + r * W_);
                s += v.x + v.y + v.z + v.w;
            }
            s *= (1.f / 16.f);
        }
        if (ch < C_) fibf[((size_t)b * KPP + k) * C_ + ch] = __float2bfloat16(s);
        else         si[(size_t)b * 2 * KPP + (ch - C_) * KPP + k] = s;
    } else {
        int t6 = gid - 6544;
        int b = t6 / 576;
        int rem = t6 % 576;
        int c0 = (rem / 144) * 64, p0 = (rem % 144) * 64;
        const float* src = cur_embed + ((size_t)b * C_ + c0) * HW_ + p0;
        #pragma unroll
        for (int it = 0; it < 4; it++) {
            int f = t + it * 256;
            int cl = f >> 4, p4 = (f & 15) * 4;
            float4 v = *reinterpret_cast<const float4*>(src + (size_t)cl * HW_ + p4);
            int pc = 4 * (((p4 >> 2) ^ (cl >> 2)) & 15);
            *reinterpret_cast<float4*>(&tile[cl][pc]) = v;
        }
        __syncthreads();
        bf16* dst = curbf + ((size_t)b * HW_ + p0) * 256 + c0;
        #pragma unroll
        for (int it = 0; it < 4; it++) {
            int f = t + it * 256;
            int pl = f >> 4, c4 = (f & 15) * 4;
            int col = (pl & 3) + 4 * (((pl >> 2) ^ (c4 >> 2)) & 15);
            ushort4 u;
            u.x = bfb(tile[c4 + 0][col]); u.y = bfb(tile[c4 + 1][col]);
            u.z = bfb(tile[c4 + 2][col]); u.w = bfb(tile[c4 + 3][col]);
            *reinterpret_cast<ushort4*>(dst + (size_t)pl * 256 + c4) = u;
        }
    }
}

// ---------------------------------------------------------------- mixA ----
// [0,768): gmap ; [768,1920): tcurP batches {0,1} -> dsthalf (prevbfA).
__global__ __launch_bounds__(256)
void mixA_kernel(const bf16* __restrict__ curbf, const bf16* __restrict__ fibf,
                 const float* __restrict__ si, float* __restrict__ gout,
                 const float* __restrict__ prev_embed, bf16* __restrict__ dsthalf)
{
    __shared__ __align__(16) char Smem[30720];
    int gid = blockIdx.x;
    int tid = threadIdx.x;
    if (gid < 768) {
        bf16* Abuf = (bf16*)Smem;                 // 16384 B
        bf16* Bbuf = (bf16*)(Smem + 16384);       // 12288 B
        float* bred = (float*)(Smem + 28672);     // 1536 B : [wm][wn][s][48]
        int b = gid & 7;
        int p0 = (gid >> 3) * 96;
        int lane = tid & 63;
        int w = tid >> 6, wm = w & 1, wn = w >> 1;
        int l15 = lane & 15, lk = lane >> 4;
        const bf16* fb = fibf + (size_t)b * KPP * 256;
        const bf16* cb = curbf + (size_t)b * HW_ * 256;
        const float* sib = si + (size_t)b * 2 * KPP;

        int wbase = tid & 192;
        int t3 = (tid >> 3) & 7;
        int cX = (tid & 7) ^ t3;
        int r0 = tid >> 3;
        int swzE0 = ((lk) ^ (l15 & 7)) * 8;
        int swzE1 = ((4 + lk) ^ (l15 & 7)) * 8;

        float best[2][3];
        #pragma unroll
        for (int s = 0; s < 2; s++)
            #pragma unroll
            for (int nt = 0; nt < 3; nt++) best[s][nt] = -INFINITY;
        f32x4 acc[4][3] = {};

        for (int q = 0; q < 20; ++q) {
            {   // STAGE
                int chunk = q >> 2, ks = q & 3;
                int koff = ks * 64 + cX * 8;
                #pragma unroll
                for (int i = 0; i < 4; i++) {
                    int row = i * 32 + r0;
                    gload_lds16(fb + (size_t)(chunk * 128 + row) * 256 + koff,
                                &Abuf[(size_t)(i * 256 + wbase) * 8]);
                }
                #pragma unroll
                for (int i = 0; i < 3; i++) {
                    int row = i * 32 + r0;
                    gload_lds16(cb + (size_t)(p0 + row) * 256 + koff,
                                &Bbuf[(size_t)(i * 256 + wbase) * 8]);
                }
            }
            __syncthreads();
            {   // COMPUTE
                #pragma unroll
                for (int k = 0; k < 2; k++) {
                    int swz = k ? swzE1 : swzE0;
                    short8 a[4], bq[3];
                    #pragma unroll
                    for (int mt = 0; mt < 4; mt++)
                        a[mt] = *reinterpret_cast<const short8*>(
                            &Abuf[(size_t)(wm * 64 + mt * 16 + l15) * 64 + swz]);
                    #pragma unroll
                    for (int nt = 0; nt < 3; nt++)
                        bq[nt] = *reinterpret_cast<const short8*>(
                            &Bbuf[(size_t)(wn * 48 + nt * 16 + l15) * 64 + swz]);
                    #pragma unroll
                    for (int mt = 0; mt < 4; mt++)
                        #pragma unroll
                        for (int nt = 0; nt < 3; nt++)
                            acc[mt][nt] = __builtin_amdgcn_mfma_f32_16x16x32_bf16(
                                a[mt], bq[nt], acc[mt][nt], 0, 0, 0);
                }
            }
            if ((q & 3) == 3) {
                int kp0 = (q >> 2) * 128;
                #pragma unroll
                for (int mt = 0; mt < 4; mt++) {
                    int rb = kp0 + wm * 64 + mt * 16 + lk * 4;
                    float4 s0 = *reinterpret_cast<const float4*>(sib + rb);
                    float4 s1 = *reinterpret_cast<const float4*>(sib + KPP + rb);
                    const float* s0p = reinterpret_cast<const float*>(&s0);
                    const float* s1p = reinterpret_cast<const float*>(&s1);
                    #pragma unroll
                    for (int nt = 0; nt < 3; nt++) {
                        #pragma unroll
                        for (int r = 0; r < 4; r++) {
                            float v = acc[mt][nt][r];
                            best[0][nt] = fmaxf(best[0][nt], v * s0p[r]);
                            best[1][nt] = fmaxf(best[1][nt], v * s1p[r]);
                        }
                        acc[mt][nt] = (f32x4){0.f, 0.f, 0.f, 0.f};
                    }
                }
            }
            __syncthreads();
        }
        #pragma unroll
        for (int s = 0; s < 2; s++)
            #pragma unroll
            for (int nt = 0; nt < 3; nt++) {
                float v = best[s][nt];
                v = fmaxf(v, __shfl_xor(v, 16));
                v = fmaxf(v, __shfl_xor(v, 32));
                if (lk == 0) bred[((wm * 2 + wn) * 2 + s) * 48 + nt * 16 + l15] = v;
            }
        __syncthreads();
        if (tid < 192) {
            int s2 = tid / 96, pxl = tid % 96;
            int wn2 = pxl / 48, j = pxl % 48;
            float v = fmaxf(bred[((0 * 2 + wn2) * 2 + s2) * 48 + j],
                            bred[((1 * 2 + wn2) * 2 + s2) * 48 + j]);
            gout[((size_t)b * 2 + s2) * HW_ + p0 + pxl] = v;
        }
    } else {
        float (*tile)[68] = (float(*)[68])Smem;
        int tp = gid - 768;                   // [0,1152): batches 0,1
        int b_l = tp / 576;
        int rem = tp % 576;
        int c0 = (rem / 144) * 64, p0 = (rem % 144) * 64;
        const float* src = prev_embed + ((size_t)b_l * C_ + c0) * HW_ + p0;
        #pragma unroll
        for (int it = 0; it < 4; it++) {
            int f = tid + it * 256;
            int cl = f >> 4, p4 = (f & 15) * 4;
            float4 v = *reinterpret_cast<const float4*>(src + (size_t)cl * HW_ + p4);
            int pc = 4 * (((p4 >> 2) ^ (cl >> 2)) & 15);
            *reinterpret_cast<float4*>(&tile[cl][pc]) = v;
        }
        __syncthreads();
        bf16* dst = dsthalf + ((size_t)b_l * HW_ + p0) * 256 + c0;
        #pragma unroll
        for (int it = 0; it < 4; it++) {
            int f = tid + it * 256;
            int pl = f >> 4, c4 = (f & 15) * 4;
            int col = (pl & 3) + 4 * (((pl >> 2) ^ (c4 >> 2)) & 15);
            ushort4 u;
            u.x = bfb(tile[c4 + 0][col]); u.y = bfb(tile[c4 + 1][col]);
            u.z = bfb(tile[c4 + 2][col]); u.w = bfb(tile[c4 + 3][col]);
            *reinterpret_cast<ushort4*>(dst + (size_t)pl * 256 + c4) = u;
        }
    }
}

// ---------------------------------------------------------------- mixB ----
// [0,288): lmap (2 batches from lmap_pb, global b0 = lmap_b0) ;
// [288,1440): tcurP batches {tcur_g2, tcur_g2+1} -> tcur_dst.
__global__ __launch_bounds__(256)
void mixB_kernel(const bf16* __restrict__ curbf, const bf16* __restrict__ lmap_pb,
                 const bf16* __restrict__ zbuf, const float* __restrict__ prev_seg,
                 float* __restrict__ lout, int lmap_b0,
                 const float* __restrict__ prev_embed, int tcur_g2,
                 bf16* __restrict__ tcur_dst)
{
    constexpr int GSTR = 258;
    __shared__ __align__(16) char Smem[40960];
    int gid = blockIdx.x;
    int tid = threadIdx.x;
    if (gid < 288) {
        bf16* Abuf = (bf16*)Smem;
        bf16* Bbuf = (bf16*)(Smem + 8192);
        bf16* Gb   = (bf16*)Smem;
        float* segf = (float*)(Smem + 33024);
        float* redf = (float*)(Smem + 35072);

        int lb = gid / 144, tile_ = gid % 144;
        int b = lmap_b0 + lb;
        const bf16* pb = lmap_pb + (size_t)lb * HW_ * 256;
        const bf16* cb = curbf + (size_t)b * HW_ * 256;
        int ty0 = (tile_ / 12) * 8, tx0 = (tile_ % 12) * 8;
        int lane = tid & 63, wn = tid >> 6;
        int l15 = lane & 15, lk = lane >> 4;

        int wbase = tid & 192;
        int t3 = (tid >> 3) & 7;
        int cX = (tid & 7) ^ t3;
        int r0 = tid >> 3;
        int swzE0 = ((lk) ^ (l15 & 7)) * 8;
        int swzE1 = ((4 + lk) ^ (l15 & 7)) * 8;

        int gpxA0 = (ty0 + (r0 >> 3)) * W_ + tx0 + (r0 & 7);
        int gpxA1 = (ty0 + (r0 >> 3) + 4) * W_ + tx0 + (r0 & 7);
        const bf16* rowB[8];
        #pragma unroll
        for (int i = 0; i < 8; i++) {
            int wrow = i * 32 + r0;
            int wy = wrow >> 4, wx = wrow & 15;
            int gy = ty0 - 4 + wy, gx = tx0 - 4 + wx;
            bool ok = (gy >= 0) && (gy < H_) && (gx >= 0) && (gx < W_);
            rowB[i] = ok ? (pb + (size_t)(gy * W_ + gx) * 256) : zbuf;
        }

        f32x4 acc[4][4] = {};

        for (int ks = 0; ks < 4; ++ks) {
            int koff = ks * 64 + cX * 8;
            gload_lds16(cb + (size_t)gpxA0 * 256 + koff, &Abuf[(size_t)(wbase) * 8]);
            gload_lds16(cb + (size_t)gpxA1 * 256 + koff, &Abuf[(size_t)(256 + wbase) * 8]);
            #pragma unroll
            for (int i = 0; i < 8; i++)
                gload_lds16(rowB[i] + koff, &Bbuf[(size_t)(i * 256 + wbase) * 8]);
            __syncthreads();
            #pragma unroll
            for (int k = 0; k < 2; k++) {
                int swz = k ? swzE1 : swzE0;
                short8 a[4], bq[4];
                #pragma unroll
                for (int mt = 0; mt < 4; mt++)
                    a[mt] = *reinterpret_cast<const short8*>(
                        &Abuf[(size_t)(mt * 16 + l15) * 64 + swz]);
                #pragma unroll
                for (int nt = 0; nt < 4; nt++)
                    bq[nt] = *reinterpret_cast<const short8*>(
                        &Bbuf[(size_t)(wn * 64 + nt * 16 + l15) * 64 + swz]);
                #pragma unroll
                for (int mt = 0; mt < 4; mt++)
                    #pragma unroll
                    for (int nt = 0; nt < 4; nt++)
                        acc[mt][nt] = __builtin_amdgcn_mfma_f32_16x16x32_bf16(
                            a[mt], bq[nt], acc[mt][nt], 0, 0, 0);
            }
            __syncthreads();
        }

        #pragma unroll
        for (int mt = 0; mt < 4; mt++)
            #pragma unroll
            for (int nt = 0; nt < 4; nt++)
                #pragma unroll
                for (int r = 0; r < 4; r++)
                    Gb[(mt * 16 + lk * 4 + r) * GSTR + wn * 64 + nt * 16 + l15] =
                        __float2bfloat16(acc[mt][nt][r]);
        #pragma unroll
        for (int it = 0; it < 2; it++) {
            int f = tid + it * 256;
            int s = f >> 8, wp = f & 255;
            int wy = wp >> 4, wx = wp & 15;
            int gy = ty0 - 4 + wy, gxx = tx0 - 4 + wx;
            float v = 0.f;
            if (gy >= 0 && gy < H_ && gxx >= 0 && gxx < W_)
                v = prev_seg[((size_t)b * 2 + s) * HW_ + gy * W_ + gxx] * (1.f / 256.f);
            segf[f] = v;
        }
        __syncthreads();
        {
            int m = tid & 63;
            int sh = tid >> 6;
            int s = sh >> 1, hh = sh & 1;
            int py = m >> 3, lx = m & 7;
            const bf16* gr = Gb + (size_t)m * GSTR;
            const float* sr = segf + s * 256;
            float mx = -INFINITY;
            int wr0 = hh * 5, wr1 = hh ? 9 : 5;
            for (int wr = wr0; wr < wr1; ++wr) {
                int base = (py + wr) * 16 + lx;
                #pragma unroll
                for (int wc = 0; wc < 9; ++wc)
                    mx = fmaxf(mx, __bfloat162float(gr[base + wc]) * sr[base + wc]);
            }
            redf[sh * 64 + m] = mx;
        }
        __syncthreads();
        if (tid < 128) {
            int s = tid >> 6, m = tid & 63;
            float v = fmaxf(redf[(s * 2 + 0) * 64 + m], redf[(s * 2 + 1) * 64 + m]);
            int gpx = (ty0 + (m >> 3)) * W_ + tx0 + (m & 7);
            lout[((size_t)b * 2 + s) * HW_ + gpx] = v;
        }
    } else {
        float (*tile)[68] = (float(*)[68])Smem;
        int tp = gid - 288;
        int b_l = tp / 576;
        int rem = tp % 576;
        int c0 = (rem / 144) * 64, p0 = (rem % 144) * 64;
        const float* src = prev_embed + ((size_t)(tcur_g2 + b_l) * C_ + c0) * HW_ + p0;
        #pragma unroll
        for (int it = 0; it < 4; it++) {
            int f = tid + it * 256;
            int cl = f >> 4, p4 = (f & 15) * 4;
            float4 v = *reinterpret_cast<const float4*>(src + (size_t)cl * HW_ + p4);
            int pc = 4 * (((p4 >> 2) ^ (cl >> 2)) & 15);
            *reinterpret_cast<float4*>(&tile[cl][pc]) = v;
        }
        __syncthreads();
        bf16* dst = tcur_dst + ((size_t)b_l * HW_ + p0) * 256 + c0;
        #pragma unroll
        for (int it = 0; it < 4; it++) {
            int f = tid + it * 256;
            int pl = f >> 4, c4 = (f & 15) * 4;
            int col = (pl & 3) + 4 * (((pl >> 2) ^ (c4 >> 2)) & 15);
            ushort4 u;
            u.x = bfb(tile[c4 + 0][col]); u.y = bfb(tile[c4 + 1][col]);
            u.z = bfb(tile[c4 + 2][col]); u.w = bfb(tile[c4 + 3][col]);
            *reinterpret_cast<ushort4*>(dst + (size_t)pl * 256 + c4) = u;
        }
    }
}

// ---------------------------------------------------------------- packall ----
__global__ __launch_bounds__(256)
void packall_kernel(const float* __restrict__ dec,
                    const float* __restrict__ gout, const float* __restrict__ lout,
                    const float* __restrict__ init_seg, const float* __restrict__ prev_seg,
                    bf16* __restrict__ hcat8, bf16* __restrict__ hcat1,
                    bf16* __restrict__ hmidp)
{
    __shared__ float tile[64][68];
    int gid = blockIdx.x;
    int t = threadIdx.x;
    if (gid < 4608) {
        int b = gid / 576;
        int rem = gid % 576;
        int c0 = (rem / 144) * 64, p0 = (rem % 144) * 64;
        const float* src = dec + ((size_t)b * C_ + c0) * HW_ + p0;
        #pragma unroll
        for (int it = 0; it < 4; it++) {
            int f = t + it * 256;
            int cl = f >> 4, p4 = (f & 15) * 4;
            float4 v = *reinterpret_cast<const float4*>(src + (size_t)cl * HW_ + p4);
            int pc = 4 * (((p4 >> 2) ^ (cl >> 2)) & 15);
            *reinterpret_cast<float4*>(&tile[cl][pc]) = v;
        }
        __syncthreads();
        #pragma unroll
        for (int it = 0; it < 4; it++) {
            int f = t + it * 256;
            int pl = f >> 4, c4 = (f & 15) * 4;
            int p = p0 + pl;
            int y = p / 96, x = p % 96;
            int pos = (y + 1) * HP_ + x + 1;
            int ch = c0 + c4;
            int col = (pl & 3) + 4 * (((pl >> 2) ^ (c4 >> 2)) & 15);
            ushort4 u;
            u.x = bfb(tile[c4 + 0][col]); u.y = bfb(tile[c4 + 1][col]);
            u.z = bfb(tile[c4 + 2][col]); u.w = bfb(tile[c4 + 3][col]);
            bf16* dst = hcat8 + ((size_t)b * 8 + (ch >> 5)) * CHK + (size_t)pos * 32 + (ch & 31);
            *reinterpret_cast<ushort4*>(dst) = u;
        }
    } else if (gid < 4896) {
        int idx = (gid - 4608) * 256 + t;
        int b = idx / HW_, p = idx % HW_;
        int y = p / 96, x = p % 96;
        int pos = (y + 1) * HP_ + x + 1;
        bf16* dst = hcat1 + ((size_t)b * HPW + pos) * 8;
        float g0 = gout[((size_t)b * 2 + 0) * HW_ + p];
        float g1 = gout[((size_t)b * 2 + 1) * HW_ + p];
        float i0 = init_seg[((size_t)b * 2 + 0) * HW_ + p];
        float i1 = init_seg[((size_t)b * 2 + 1) * HW_ + p];
        float l0 = lout[((size_t)b * 2 + 0) * HW_ + p];
        float l1 = lout[((size_t)b * 2 + 1) * HW_ + p];
        float q0 = prev_seg[((size_t)b * 2 + 0) * HW_ + p];
        float q1 = prev_seg[((size_t)b * 2 + 1) * HW_ + p];
        ushort4 u; u.x = bfb(g0); u.y = bfb(g1); u.z = bfb(i0); u.w = bfb(i1);
        *reinterpret_cast<ushort4*>(dst) = u;
        ushort4 u2; u2.x = bfb(l0); u2.y = bfb(l1); u2.z = bfb(q0); u2.w = bfb(q1);
        *reinterpret_cast<ushort4*>(dst + 4) = u2;
    } else {
        int idx = (gid - 4896) * 256 + t;
        if (idx >= B_ * 388) return;
        int b = idx / 388, bi = idx % 388;
        int pos;
        if (bi < 98) pos = bi;
        else if (bi < 196) pos = 97 * HP_ + (bi - 98);
        else if (bi < 292) pos = (bi - 196 + 1) * HP_;
        else pos = (bi - 292 + 1) * HP_ + 97;
        const short8 Z = {0, 0, 0, 0, 0, 0, 0, 0};
        #pragma unroll
        for (int c = 0; c < 8; c++) {
            bf16* p = hcat8 + ((size_t)b * 8 + c) * CHK + (size_t)pos * 32;
            #pragma unroll
            for (int j = 0; j < 4; j++)
                *reinterpret_cast<short8*>(p + j * 8) = Z;
        }
        *reinterpret_cast<short8*>(hcat1 + ((size_t)b * HPW + pos) * 8) = Z;
        bf16* q = hmidp + ((size_t)b * HPW + pos) * 128;
        #pragma unroll
        for (int j = 0; j < 16; j++)
            *reinterpret_cast<short8*>(q + j * 8) = Z;
    }
}

// ---------------------------------------------------------------- conv1 ----
__global__ __launch_bounds__(256)
void conv1_mfma(const bf16* __restrict__ hcat8, const bf16* __restrict__ hcat1,
                const bf16* __restrict__ w1bf, const float* __restrict__ b1,
                bf16* __restrict__ hmidp)
{
    __shared__ bf16 S[14336];
    bf16* Abuf = S;
    bf16* Bbuf = S + 8192;
    int gid = blockIdx.x;                     // 768 = 8 b x 96 rows
    int b = gid & 7;
    int row = gid >> 3;
    int tid = threadIdx.x, lane = tid & 63;
    int w = tid >> 6, wm = w & 1, wn = w >> 1;
    int l15 = lane & 15, lk = lane >> 4;
    const bf16* hb8 = hcat8 + (size_t)b * 8 * CHK;
    const bf16* hb1 = hcat1 + (size_t)b * HPW * 8;

    int wbase = tid & 192;
    int t3 = (tid >> 3) & 7;
    int cX = (tid & 7) ^ t3;
    int selX = cX >> 2;
    int cin8 = (cX & 3) * 8;
    int r0 = tid >> 3;
    int swzE0 = ((lk) ^ (l15 & 7)) * 8;
    int swzE1 = ((4 + lk) ^ (l15 & 7)) * 8;

    f32x4 acc[4][3] = {};

    auto STAGE = [&](int p) {
        int s0 = 2 * p, s1 = s0 + 1;
        int icc0 = s0 / 9, tap0 = s0 - icc0 * 9;
        int icc1 = s1 / 9, tap1 = s1 - icc1 * 9;
        const bf16* gA = w1bf + (size_t)p * 8192 + (size_t)selX * 4096 + cin8;
        #pragma unroll
        for (int i = 0; i < 4; i++)
            gload_lds16(gA + (i * 32 + r0) * 32,
                        &Abuf[(size_t)(i * 256 + wbase) * 8]);
        int tapS = selX ? tap1 : tap0;
        int iccS = selX ? icc1 : icc0;
        int posT = (row + tapS / 3) * HP_ + (tapS % 3);
        bool is8 = (iccS >= 8);
        const bf16* gb = is8 ? hb1 : (hb8 + (size_t)iccS * CHK);
        #pragma unroll
        for (int i = 0; i < 3; i++) {
            int c = i * 32 + r0;
            const bf16* g = is8 ? (gb + (size_t)(posT + c) * 8)
                                : (gb + (size_t)(posT + c) * 32 + cin8);
            gload_lds16(g, &Bbuf[(size_t)(i * 256 + wbase) * 8]);
        }
    };

    auto COMPUTE = [&]() {
        #pragma unroll
        for (int k = 0; k < 2; k++) {
            int swz = k ? swzE1 : swzE0;
            short8 a[4], bq[3];
            #pragma unroll
            for (int mt = 0; mt < 4; mt++)
                a[mt] = *reinterpret_cast<const short8*>(
                    &Abuf[(size_t)(wm * 64 + mt * 16 + l15) * 64 + swz]);
            #pragma unroll
            for (int nt = 0; nt < 3; nt++)
                bq[nt] = *reinterpret_cast<const short8*>(
                    &Bbuf[(size_t)(wn * 48 + nt * 16 + l15) * 64 + swz]);
            #pragma unroll
            for (int mt = 0; mt < 4; mt++)
                #pragma unroll
                for (int nt = 0; nt < 3; nt++)
                    acc[mt][nt] = __builtin_amdgcn_mfma_f32_16x16x32_bf16(
                        a[mt], bq[nt], acc[mt][nt], 0, 0, 0);
        }
    };

    for (int p = 0; p < 41; ++p) {
        STAGE(p);
        __syncthreads();
        COMPUTE();
        __syncthreads();
    }

    #pragma unroll
    for (int nt = 0; nt < 3; nt++) {
        int pxl = wn * 48 + nt * 16 + l15;
        #pragma unroll
        for (int mt = 0; mt < 4; mt++) {
            int ocb = wm * 64 + mt * 16 + lk * 4;
            float4 bias = *reinterpret_cast<const float4*>(b1 + ocb);
            const float* bp = reinterpret_cast<const float*>(&bias);
            ushort4 u;
            u.x = bfb(fmaxf(acc[mt][nt][0] + bp[0], 0.f));
            u.y = bfb(fmaxf(acc[mt][nt][1] + bp[1], 0.f));
            u.z = bfb(fmaxf(acc[mt][nt][2] + bp[2], 0.f));
            u.w = bfb(fmaxf(acc[mt][nt][3] + bp[3], 0.f));
            int chunk = (ocb >> 3) ^ (pxl & 7);
            *reinterpret_cast<ushort4*>(&S[(size_t)pxl * 128 + chunk * 8 + (lk & 1) * 4]) = u;
        }
    }
    __syncthreads();
    {
        bf16* dst = hmidp + (size_t)b * HPW * 128 + ((size_t)(row + 1) * HP_ + 1) * 128;
        #pragma unroll
        for (int i = 0; i < 6; i++) {
            int f = tid + i * 256;
            int px = f >> 4, cc = f & 15;
            short8 v = *reinterpret_cast<const short8*>(
                &S[(size_t)px * 128 + (cc ^ (px & 7)) * 8]);
            *reinterpret_cast<short8*>(dst + (size_t)f * 8) = v;
        }
    }
}

// ---------------------------------------------------------------- conv2 ----
__global__ __launch_bounds__(128)
void conv2_mfma(const bf16* __restrict__ hmidp, const bf16* __restrict__ w2bf,
                const float* __restrict__ b2, float* __restrict__ out)
{
    __shared__ bf16 Abuf[1024];
    __shared__ bf16 Bbuf[6144];
    int gid = blockIdx.x;             // 768 = 8 b x 96 rows
    int b = gid & 7;
    int y = gid >> 3;
    int p0 = y * 96;
    int tid = threadIdx.x, lane = tid & 63;
    int wn = tid >> 6;
    int l15 = lane & 15, lk = lane >> 4;
    const bf16* hb = hmidp + (size_t)b * HPW * 128;

    int wbase = tid & 64;
    int t3 = (tid >> 3) & 7;
    int cX = (tid & 7) ^ t3;
    int r0 = tid >> 3;
    int swzE0 = ((lk) ^ (l15 & 7)) * 8;
    int swzE1 = ((4 + lk) ^ (l15 & 7)) * 8;

    f32x4 acc[3] = {};

    auto STAGE = [&](int s) {
        int tap = s >> 1, half = s & 1;
        int toff = (tap / 3) * HP_ + (tap % 3);
        gload_lds16(w2bf + ((size_t)s * 16 + r0) * 64 + cX * 8,
                    &Abuf[(size_t)wbase * 8]);
        #pragma unroll
        for (int i = 0; i < 6; i++) {
            int c = i * 16 + r0;
            gload_lds16(hb + (size_t)(y * HP_ + c + toff) * 128 + half * 64 + cX * 8,
                        &Bbuf[(size_t)(i * 128 + wbase) * 8]);
        }
    };

    auto COMPUTE = [&]() {
        #pragma unroll
        for (int k = 0; k < 2; k++) {
            int swz = k ? swzE1 : swzE0;
            short8 a = *reinterpret_cast<const short8*>(&Abuf[(size_t)l15 * 64 + swz]);
            #pragma unroll
            for (int nt = 0; nt < 3; nt++) {
                short8 bq = *reinterpret_cast<const short8*>(
                    &Bbuf[(size_t)(wn * 48 + nt * 16 + l15) * 64 + swz]);
                acc[nt] = __builtin_amdgcn_mfma_f32_16x16x32_bf16(a, bq, acc[nt], 0, 0, 0);
            }
        }
    };

    for (int s = 0; s < 18; ++s) {
        STAGE(s);
        __syncthreads();
        COMPUTE();
        __syncthreads();
    }

    if (lk == 0) {
        float bb0 = b2[0], bb1 = b2[1];
        #pragma unroll
        for (int nt = 0; nt < 3; nt++) {
            int px = p0 + wn * 48 + nt * 16 + l15;
            out[((size_t)b * 2 + 0) * HW_ + px] = acc[nt][0] + bb0;
            out[((size_t)b * 2 + 1) * HW_ + px] = acc[nt][1] + bb1;
        }
    }
}

// ---------------------------------------------------------------- launch ----
extern "C" void kernel_launch(void* const* d_in, const int* in_sizes, int n_in,
                              void* d_out, int out_size, void* d_ws, size_t ws_size,
                              hipStream_t stream)
{
    const float* cur_embed  = (const float*)d_in[0];
    const float* cur_decode = (const float*)d_in[1];
    const float* init_embed = (const float*)d_in[2];
    const float* init_seg   = (const float*)d_in[3];
    const float* prev_embed = (const float*)d_in[4];
    const float* prev_seg   = (const float*)d_in[5];
    const float* W1 = (const float*)d_in[6];
    const float* b1 = (const float*)d_in[7];
    const float* W2 = (const float*)d_in[8];
    const float* b2 = (const float*)d_in[9];
    float* out = (float*)d_out;

    char* ws = (char*)d_ws;
    bf16* hcat8 = (bf16*)ws;
    bf16* curbf = (bf16*)ws;                          // alias (dead after last lmap)
    bf16* hcat1 = (bf16*)(ws + 39337984);
    const size_t HCAT_REGION = 40567296;
    bf16* hmidp  = (bf16*)(ws + HCAT_REGION);
    bf16* fibf   = (bf16*)(ws + HCAT_REGION);         // [K1..K2]
    float* si  = (float*)(ws + HCAT_REGION + 2621440);
    bf16* prevbfB = (bf16*)(ws + 39337984);           // [K3+] 9,437,184 B
    bf16* prevbfA = (bf16*)(ws + 48775168);           // [K2+] 9,437,184 B
    bf16* w1bf = (bf16*)(ws + 60236288);
    bf16* w2bf = (bf16*)(ws + 60908032);
    float* gout = (float*)(ws + 60944896);
    float* lout = (float*)(ws + 61534720);
    const bf16* zbuf = w1bf + (size_t)81 * 4096;      // slab 81 = zeros

    prep_kernel<<<11152, 256, 0, stream>>>(W1, W2, init_embed, init_seg, cur_embed,
                                           w1bf, w2bf, fibf, si, curbf);
    mixA_kernel<<<1920, 256, 0, stream>>>(curbf, fibf, si, gout, prev_embed, prevbfA);
    mixB_kernel<<<1440, 256, 0, stream>>>(curbf, prevbfA, zbuf, prev_seg, lout, 0,
                                          prev_embed, 2, prevbfB);
    mixB_kernel<<<1440, 256, 0, stream>>>(curbf, prevbfB, zbuf, prev_seg, lout, 2,
                                          prev_embed, 4, prevbfA);
    mixB_kernel<<<1440, 256, 0, stream>>>(curbf, prevbfA, zbuf, prev_seg, lout, 4,
                                          prev_embed, 6, prevbfB);
    mixB_kernel<<<288, 256, 0, stream>>>(curbf, prevbfB, zbuf, prev_seg, lout, 6,
                                         prev_embed, 0, prevbfA);
    packall_kernel<<<4909, 256, 0, stream>>>(cur_decode, gout, lout, init_seg,
                                             prev_seg, hcat8, hcat1, hmidp);
    conv1_mfma<<<768, 256, 0, stream>>>(hcat8, hcat1, w1bf, b1, hmidp);
    conv2_mfma<<<768, 128, 0, stream>>>(hmidp, w2bf, b2, out);
}

// Round 20
// 238.585 us; speedup vs baseline: 1.0166x; 1.0166x over previous
//
#include <hip/hip_runtime.h>
#include <hip/hip_bf16.h>

// Round 20: REVERT to r18 structure (r19 mix was neutral-negative). Transpose-out
//           stores widened to 16B/thread (512B contiguous per half-wave) in prep
//           tcur-branch + tcur_kernel. Everything else byte-identical to r18.
// ws layout (62.12 MB, aliased): unchanged from r18.

typedef __hip_bfloat16 bf16;
typedef __attribute__((ext_vector_type(8))) short short8;
typedef __attribute__((ext_vector_type(4))) float f32x4;

constexpr int B_  = 8;
constexpr int C_  = 256;
constexpr int H_  = 96;
constexpr int W_  = 96;
constexpr int HW_ = H_ * W_;       // 9216
constexpr int PW_ = 24;
constexpr int KP_ = 576;
constexpr int KPP = 640;
constexpr int HP_ = 98;
constexpr int HPW = HP_ * HP_;     // 9604
constexpr int CHK = HPW * 32;

__device__ __forceinline__ unsigned short bfb(float f) {
    bf16 h = __float2bfloat16(f);
    return *reinterpret_cast<unsigned short*>(&h);
}

__device__ __forceinline__ void gload_lds16(const bf16* g, bf16* l) {
    __builtin_amdgcn_global_load_lds((const void*)g, (void*)l, 16, 0, 0);
}

// 16B-coalesced swizzled transpose-out: tile[64ch][68] -> dst[64px][256ch] slice
__device__ __forceinline__ void twrite16(const float (*tile)[68], bf16* dst, int t)
{
    #pragma unroll
    for (int it = 0; it < 2; it++) {
        int f = t + it * 256;                 // 0..511 : 64 px x 8 ch-groups
        int pl = f >> 3, c8 = f & 7;
        int qA = c8 * 2, qB = qA + 1;
        int colA = (pl & 3) + 4 * (((pl >> 2) ^ qA) & 15);
        int colB = (pl & 3) + 4 * (((pl >> 2) ^ qB) & 15);
        short8 v;
        v[0] = (short)bfb(tile[c8 * 8 + 0][colA]);
        v[1] = (short)bfb(tile[c8 * 8 + 1][colA]);
        v[2] = (short)bfb(tile[c8 * 8 + 2][colA]);
        v[3] = (short)bfb(tile[c8 * 8 + 3][colA]);
        v[4] = (short)bfb(tile[c8 * 8 + 4][colB]);
        v[5] = (short)bfb(tile[c8 * 8 + 5][colB]);
        v[6] = (short)bfb(tile[c8 * 8 + 6][colB]);
        v[7] = (short)bfb(tile[c8 * 8 + 7][colB]);
        *reinterpret_cast<short8*>(dst + (size_t)pl * 256 + c8 * 8) = v;
    }
}

// ------------------------------------------------------------ prep ----
// blocks [0,1384): W1/W2 convert ; [1384,6544): pool ; [6544,11152): tcur(cur).
__global__ __launch_bounds__(256)
void prep_kernel(const float* __restrict__ W1, const float* __restrict__ W2,
                 const float* __restrict__ init_embed, const float* __restrict__ init_seg,
                 const float* __restrict__ cur_embed,
                 bf16* __restrict__ w1bf, bf16* __restrict__ w2bf,
                 bf16* __restrict__ fibf, float* __restrict__ si,
                 bf16* __restrict__ curbf)
{
    __shared__ float tile[64][68];
    int gid = blockIdx.x;
    int t = threadIdx.x;
    if (gid < 1384) {
        int idx = gid * 256 + t;
        if (idx < 82 * 128 * 32) {
            int ic = idx & 31;
            int oc = (idx >> 5) & 127;
            int ks = idx >> 12;
            int icc = ks / 9, tap = ks % 9;
            int icg = icc * 32 + ic;
            float v = (icg < 264) ? W1[((size_t)oc * 264 + icg) * 9 + tap] : 0.f;
            w1bf[idx] = __float2bfloat16(v);
        } else {
            int j = idx - 82 * 128 * 32;
            if (j >= 18 * 16 * 64) return;
            int c  = j & 63;
            int oc = (j >> 6) & 15;
            int s  = j >> 10;
            int tap = s >> 1, half = s & 1;
            float v = (oc < 2) ? W2[((size_t)oc * 128 + half * 64 + c) * 9 + tap] : 0.f;
            w2bf[j] = __float2bfloat16(v);
        }
    } else if (gid < 6544) {
        int idx = (gid - 1384) * 256 + t;
        int k  = idx % KPP;
        int ch = (idx / KPP) % (C_ + 2);
        int b  = idx / (KPP * (C_ + 2));
        float s = 0.f;
        if (k < KP_) {
            int ph = k / PW_, pw = k % PW_;
            const float* src = (ch < C_)
                ? (init_embed + (((size_t)b * C_ + ch) * H_ + ph * 4) * W_ + pw * 4)
                : (init_seg   + (((size_t)b * 2 + (ch - C_)) * H_ + ph * 4) * W_ + pw * 4);
            #pragma unroll
            for (int r = 0; r < 4; r++) {
                float4 v = *reinterpret_cast<const float4*>(src + r * W_);
                s += v.x + v.y + v.z + v.w;
            }
            s *= (1.f / 16.f);
        }
        if (ch < C_) fibf[((size_t)b * KPP + k) * C_ + ch] = __float2bfloat16(s);
        else         si[(size_t)b * 2 * KPP + (ch - C_) * KPP + k] = s;
    } else {
        int t6 = gid - 6544;
        int b = t6 / 576;
        int rem = t6 % 576;
        int c0 = (rem / 144) * 64, p0 = (rem % 144) * 64;
        const float* src = cur_embed + ((size_t)b * C_ + c0) * HW_ + p0;
        #pragma unroll
        for (int it = 0; it < 4; it++) {
            int f = t + it * 256;
            int cl = f >> 4, p4 = (f & 15) * 4;
            float4 v = *reinterpret_cast<const float4*>(src + (size_t)cl * HW_ + p4);
            int pc = 4 * (((p4 >> 2) ^ (cl >> 2)) & 15);
            *reinterpret_cast<float4*>(&tile[cl][pc]) = v;
        }
        __syncthreads();
        twrite16(tile, curbf + ((size_t)b * HW_ + p0) * 256 + c0, t);
    }
}

// ------------------------------------------------------- NCHW->NHWC bf16 ----
__global__ __launch_bounds__(256)
void tcur_kernel(const float* __restrict__ cur, bf16* __restrict__ curbf)
{
    __shared__ float tile[64][68];
    int b = blockIdx.z, c0 = blockIdx.y * 64, p0 = blockIdx.x * 64;
    int t = threadIdx.x;
    const float* src = cur + ((size_t)b * C_ + c0) * HW_ + p0;
    #pragma unroll
    for (int it = 0; it < 4; it++) {
        int f = t + it * 256;
        int cl = f >> 4, p4 = (f & 15) * 4;
        float4 v = *reinterpret_cast<const float4*>(src + (size_t)cl * HW_ + p4);
        int pc = 4 * (((p4 >> 2) ^ (cl >> 2)) & 15);
        *reinterpret_cast<float4*>(&tile[cl][pc]) = v;
    }
    __syncthreads();
    twrite16(tile, curbf + ((size_t)b * HW_ + p0) * 256 + c0, t);
}

// ---------------------------------------------------------------- gmap ----
__global__ __launch_bounds__(256)
void gmap_mfma(const bf16* __restrict__ curbf, const bf16* __restrict__ fibf,
               const float* __restrict__ si, float* __restrict__ gout)
{
    __shared__ bf16 Abuf[8192];
    __shared__ bf16 Bbuf[6144];
    __shared__ float bred[2][2][2][48];
    int gid = blockIdx.x;             // 768 = 8 b x 96 px-tiles
    int b = gid & 7;
    int p0 = (gid >> 3) * 96;
    int tid = threadIdx.x, lane = tid & 63;
    int w = tid >> 6, wm = w & 1, wn = w >> 1;
    int l15 = lane & 15, lk = lane >> 4;
    const bf16* fb = fibf + (size_t)b * KPP * 256;
    const bf16* cb = curbf + (size_t)b * HW_ * 256;
    const float* sib = si + (size_t)b * 2 * KPP;

    int wbase = tid & 192;
    int t3 = (tid >> 3) & 7;
    int cX = (tid & 7) ^ t3;
    int r0 = tid >> 3;
    int swzE0 = ((lk) ^ (l15 & 7)) * 8;
    int swzE1 = ((4 + lk) ^ (l15 & 7)) * 8;

    float best[2][3];
    #pragma unroll
    for (int s = 0; s < 2; s++)
        #pragma unroll
        for (int nt = 0; nt < 3; nt++) best[s][nt] = -INFINITY;
    f32x4 acc[4][3] = {};

    auto STAGE = [&](int q) {
        int chunk = q >> 2, ks = q & 3;
        int koff = ks * 64 + cX * 8;
        #pragma unroll
        for (int i = 0; i < 4; i++) {
            int row = i * 32 + r0;
            gload_lds16(fb + (size_t)(chunk * 128 + row) * 256 + koff,
                        &Abuf[(size_t)(i * 256 + wbase) * 8]);
        }
        #pragma unroll
        for (int i = 0; i < 3; i++) {
            int row = i * 32 + r0;
            gload_lds16(cb + (size_t)(p0 + row) * 256 + koff,
                        &Bbuf[(size_t)(i * 256 + wbase) * 8]);
        }
    };

    auto COMPUTE = [&]() {
        #pragma unroll
        for (int k = 0; k < 2; k++) {
            int swz = k ? swzE1 : swzE0;
            short8 a[4], bq[3];
            #pragma unroll
            for (int mt = 0; mt < 4; mt++)
                a[mt] = *reinterpret_cast<const short8*>(
                    &Abuf[(size_t)(wm * 64 + mt * 16 + l15) * 64 + swz]);
            #pragma unroll
            for (int nt = 0; nt < 3; nt++)
                bq[nt] = *reinterpret_cast<const short8*>(
                    &Bbuf[(size_t)(wn * 48 + nt * 16 + l15) * 64 + swz]);
            #pragma unroll
            for (int mt = 0; mt < 4; mt++)
                #pragma unroll
                for (int nt = 0; nt < 3; nt++)
                    acc[mt][nt] = __builtin_amdgcn_mfma_f32_16x16x32_bf16(
                        a[mt], bq[nt], acc[mt][nt], 0, 0, 0);
        }
    };

    for (int q = 0; q < 20; ++q) {
        STAGE(q);
        __syncthreads();
        COMPUTE();
        if ((q & 3) == 3) {
            int kp0 = (q >> 2) * 128;
            #pragma unroll
            for (int mt = 0; mt < 4; mt++) {
                int rb = kp0 + wm * 64 + mt * 16 + lk * 4;
                float4 s0 = *reinterpret_cast<const float4*>(sib + rb);
                float4 s1 = *reinterpret_cast<const float4*>(sib + KPP + rb);
                const float* s0p = reinterpret_cast<const float*>(&s0);
                const float* s1p = reinterpret_cast<const float*>(&s1);
                #pragma unroll
                for (int nt = 0; nt < 3; nt++) {
                    #pragma unroll
                    for (int r = 0; r < 4; r++) {
                        float v = acc[mt][nt][r];
                        best[0][nt] = fmaxf(best[0][nt], v * s0p[r]);
                        best[1][nt] = fmaxf(best[1][nt], v * s1p[r]);
                    }
                    acc[mt][nt] = (f32x4){0.f, 0.f, 0.f, 0.f};
                }
            }
        }
        __syncthreads();
    }
    #pragma unroll
    for (int s = 0; s < 2; s++)
        #pragma unroll
        for (int nt = 0; nt < 3; nt++) {
            float v = best[s][nt];
            v = fmaxf(v, __shfl_xor(v, 16));
            v = fmaxf(v, __shfl_xor(v, 32));
            if (lk == 0) bred[wm][wn][s][nt * 16 + l15] = v;
        }
    __syncthreads();
    if (tid < 192) {
        int s2 = tid / 96, pxl = tid % 96;
        float v = fmaxf(bred[0][pxl / 48][s2][pxl % 48],
                        bred[1][pxl / 48][s2][pxl % 48]);
        gout[((size_t)b * 2 + s2) * HW_ + p0 + pxl] = v;
    }
}

// ---------------------------------------------------------------- lmap ----
__global__ __launch_bounds__(256)
void lmap_mfma(const bf16* __restrict__ curbf, const bf16* __restrict__ prevbf,
               const bf16* __restrict__ zbuf,
               const float* __restrict__ prev_seg, float* __restrict__ lout, int b0)
{
    constexpr int GSTR = 258;
    __shared__ __align__(16) char Smem[40960];
    bf16* Abuf = (bf16*)Smem;
    bf16* Bbuf = (bf16*)(Smem + 8192);
    bf16* Gb   = (bf16*)Smem;
    float* segf = (float*)(Smem + 33024);
    float* redf = (float*)(Smem + 35072);

    int b = b0 + blockIdx.y;
    const bf16* pb = prevbf + (size_t)blockIdx.y * HW_ * 256;
    const bf16* cb = curbf + (size_t)b * HW_ * 256;
    int tile = blockIdx.x;
    int ty0 = (tile / 12) * 8, tx0 = (tile % 12) * 8;
    int tid = threadIdx.x, lane = tid & 63, wn = tid >> 6;
    int l15 = lane & 15, lk = lane >> 4;

    int wbase = tid & 192;
    int t3 = (tid >> 3) & 7;
    int cX = (tid & 7) ^ t3;
    int r0 = tid >> 3;
    int swzE0 = ((lk) ^ (l15 & 7)) * 8;
    int swzE1 = ((4 + lk) ^ (l15 & 7)) * 8;

    int gpxA0 = (ty0 + (r0 >> 3)) * W_ + tx0 + (r0 & 7);
    int gpxA1 = (ty0 + (r0 >> 3) + 4) * W_ + tx0 + (r0 & 7);
    const bf16* rowB[8];
    #pragma unroll
    for (int i = 0; i < 8; i++) {
        int wrow = i * 32 + r0;
        int wy = wrow >> 4, wx = wrow & 15;
        int gy = ty0 - 4 + wy, gx = tx0 - 4 + wx;
        bool ok = (gy >= 0) && (gy < H_) && (gx >= 0) && (gx < W_);
        rowB[i] = ok ? (pb + (size_t)(gy * W_ + gx) * 256) : zbuf;
    }

    f32x4 acc[4][4] = {};

    for (int ks = 0; ks < 4; ++ks) {
        int koff = ks * 64 + cX * 8;
        gload_lds16(cb + (size_t)gpxA0 * 256 + koff, &Abuf[(size_t)(wbase) * 8]);
        gload_lds16(cb + (size_t)gpxA1 * 256 + koff, &Abuf[(size_t)(256 + wbase) * 8]);
        #pragma unroll
        for (int i = 0; i < 8; i++)
            gload_lds16(rowB[i] + koff, &Bbuf[(size_t)(i * 256 + wbase) * 8]);
        __syncthreads();
        #pragma unroll
        for (int k = 0; k < 2; k++) {
            int swz = k ? swzE1 : swzE0;
            short8 a[4], bq[4];
            #pragma unroll
            for (int mt = 0; mt < 4; mt++)
                a[mt] = *reinterpret_cast<const short8*>(
                    &Abuf[(size_t)(mt * 16 + l15) * 64 + swz]);
            #pragma unroll
            for (int nt = 0; nt < 4; nt++)
                bq[nt] = *reinterpret_cast<const short8*>(
                    &Bbuf[(size_t)(wn * 64 + nt * 16 + l15) * 64 + swz]);
            #pragma unroll
            for (int mt = 0; mt < 4; mt++)
                #pragma unroll
                for (int nt = 0; nt < 4; nt++)
                    acc[mt][nt] = __builtin_amdgcn_mfma_f32_16x16x32_bf16(
                        a[mt], bq[nt], acc[mt][nt], 0, 0, 0);
        }
        __syncthreads();
    }

    #pragma unroll
    for (int mt = 0; mt < 4; mt++)
        #pragma unroll
        for (int nt = 0; nt < 4; nt++)
            #pragma unroll
            for (int r = 0; r < 4; r++)
                Gb[(mt * 16 + lk * 4 + r) * GSTR + wn * 64 + nt * 16 + l15] =
                    __float2bfloat16(acc[mt][nt][r]);
    #pragma unroll
    for (int it = 0; it < 2; it++) {
        int f = tid + it * 256;
        int s = f >> 8, wp = f & 255;
        int wy = wp >> 4, wx = wp & 15;
        int gy = ty0 - 4 + wy, gxx = tx0 - 4 + wx;
        float v = 0.f;
        if (gy >= 0 && gy < H_ && gxx >= 0 && gxx < W_)
            v = prev_seg[((size_t)b * 2 + s) * HW_ + gy * W_ + gxx] * (1.f / 256.f);
        segf[f] = v;
    }
    __syncthreads();
    {
        int m = tid & 63;
        int sh = tid >> 6;
        int s = sh >> 1, hh = sh & 1;
        int py = m >> 3, lx = m & 7;
        const bf16* gr = Gb + (size_t)m * GSTR;
        const float* sr = segf + s * 256;
        float mx = -INFINITY;
        int wr0 = hh * 5, wr1 = hh ? 9 : 5;
        for (int wr = wr0; wr < wr1; ++wr) {
            int base = (py + wr) * 16 + lx;
            #pragma unroll
            for (int wc = 0; wc < 9; ++wc)
                mx = fmaxf(mx, __bfloat162float(gr[base + wc]) * sr[base + wc]);
        }
        redf[sh * 64 + m] = mx;
    }
    __syncthreads();
    if (tid < 128) {
        int s = tid >> 6, m = tid & 63;
        float v = fmaxf(redf[(s * 2 + 0) * 64 + m], redf[(s * 2 + 1) * 64 + m]);
        int gpx = (ty0 + (m >> 3)) * W_ + tx0 + (m & 7);
        lout[((size_t)b * 2 + s) * HW_ + gpx] = v;
    }
}

// ---------------------------------------------------------------- packall ----
__global__ __launch_bounds__(256)
void packall_kernel(const float* __restrict__ dec,
                    const float* __restrict__ gout, const float* __restrict__ lout,
                    const float* __restrict__ init_seg, const float* __restrict__ prev_seg,
                    bf16* __restrict__ hcat8, bf16* __restrict__ hcat1,
                    bf16* __restrict__ hmidp)
{
    __shared__ float tile[64][68];
    int gid = blockIdx.x;
    int t = threadIdx.x;
    if (gid < 4608) {
        int b = gid / 576;
        int rem = gid % 576;
        int c0 = (rem / 144) * 64, p0 = (rem % 144) * 64;
        const float* src = dec + ((size_t)b * C_ + c0) * HW_ + p0;
        #pragma unroll
        for (int it = 0; it < 4; it++) {
            int f = t + it * 256;
            int cl = f >> 4, p4 = (f & 15) * 4;
            float4 v = *reinterpret_cast<const float4*>(src + (size_t)cl * HW_ + p4);
            int pc = 4 * (((p4 >> 2) ^ (cl >> 2)) & 15);
            *reinterpret_cast<float4*>(&tile[cl][pc]) = v;
        }
        __syncthreads();
        #pragma unroll
        for (int it = 0; it < 4; it++) {
            int f = t + it * 256;
            int pl = f >> 4, c4 = (f & 15) * 4;
            int p = p0 + pl;
            int y = p / 96, x = p % 96;
            int pos = (y + 1) * HP_ + x + 1;
            int ch = c0 + c4;
            int col = (pl & 3) + 4 * (((pl >> 2) ^ (c4 >> 2)) & 15);
            ushort4 u;
            u.x = bfb(tile[c4 + 0][col]); u.y = bfb(tile[c4 + 1][col]);
            u.z = bfb(tile[c4 + 2][col]); u.w = bfb(tile[c4 + 3][col]);
            bf16* dst = hcat8 + ((size_t)b * 8 + (ch >> 5)) * CHK + (size_t)pos * 32 + (ch & 31);
            *reinterpret_cast<ushort4*>(dst) = u;
        }
    } else if (gid < 4896) {
        int idx = (gid - 4608) * 256 + t;
        int b = idx / HW_, p = idx % HW_;
        int y = p / 96, x = p % 96;
        int pos = (y + 1) * HP_ + x + 1;
        bf16* dst = hcat1 + ((size_t)b * HPW + pos) * 8;
        float g0 = gout[((size_t)b * 2 + 0) * HW_ + p];
        float g1 = gout[((size_t)b * 2 + 1) * HW_ + p];
        float i0 = init_seg[((size_t)b * 2 + 0) * HW_ + p];
        float i1 = init_seg[((size_t)b * 2 + 1) * HW_ + p];
        float l0 = lout[((size_t)b * 2 + 0) * HW_ + p];
        float l1 = lout[((size_t)b * 2 + 1) * HW_ + p];
        float q0 = prev_seg[((size_t)b * 2 + 0) * HW_ + p];
        float q1 = prev_seg[((size_t)b * 2 + 1) * HW_ + p];
        ushort4 u; u.x = bfb(g0); u.y = bfb(g1); u.z = bfb(i0); u.w = bfb(i1);
        *reinterpret_cast<ushort4*>(dst) = u;
        ushort4 u2; u2.x = bfb(l0); u2.y = bfb(l1); u2.z = bfb(q0); u2.w = bfb(q1);
        *reinterpret_cast<ushort4*>(dst + 4) = u2;
    } else {
        int idx = (gid - 4896) * 256 + t;
        if (idx >= B_ * 388) return;
        int b = idx / 388, bi = idx % 388;
        int pos;
        if (bi < 98) pos = bi;
        else if (bi < 196) pos = 97 * HP_ + (bi - 98);
        else if (bi < 292) pos = (bi - 196 + 1) * HP_;
        else pos = (bi - 292 + 1) * HP_ + 97;
        const short8 Z = {0, 0, 0, 0, 0, 0, 0, 0};
        #pragma unroll
        for (int c = 0; c < 8; c++) {
            bf16* p = hcat8 + ((size_t)b * 8 + c) * CHK + (size_t)pos * 32;
            #pragma unroll
            for (int j = 0; j < 4; j++)
                *reinterpret_cast<short8*>(p + j * 8) = Z;
        }
        *reinterpret_cast<short8*>(hcat1 + ((size_t)b * HPW + pos) * 8) = Z;
        bf16* q = hmidp + ((size_t)b * HPW + pos) * 128;
        #pragma unroll
        for (int j = 0; j < 16; j++)
            *reinterpret_cast<short8*>(q + j * 8) = Z;
    }
}

// ---------------------------------------------------------------- conv1 ----
__global__ __launch_bounds__(256)
void conv1_mfma(const bf16* __restrict__ hcat8, const bf16* __restrict__ hcat1,
                const bf16* __restrict__ w1bf, const float* __restrict__ b1,
                bf16* __restrict__ hmidp)
{
    __shared__ bf16 S[14336];
    bf16* Abuf = S;
    bf16* Bbuf = S + 8192;
    int gid = blockIdx.x;                     // 768 = 8 b x 96 rows
    int b = gid & 7;
    int row = gid >> 3;
    int tid = threadIdx.x, lane = tid & 63;
    int w = tid >> 6, wm = w & 1, wn = w >> 1;
    int l15 = lane & 15, lk = lane >> 4;
    const bf16* hb8 = hcat8 + (size_t)b * 8 * CHK;
    const bf16* hb1 = hcat1 + (size_t)b * HPW * 8;

    int wbase = tid & 192;
    int t3 = (tid >> 3) & 7;
    int cX = (tid & 7) ^ t3;
    int selX = cX >> 2;
    int cin8 = (cX & 3) * 8;
    int r0 = tid >> 3;
    int swzE0 = ((lk) ^ (l15 & 7)) * 8;
    int swzE1 = ((4 + lk) ^ (l15 & 7)) * 8;

    f32x4 acc[4][3] = {};

    auto STAGE = [&](int p) {
        int s0 = 2 * p, s1 = s0 + 1;
        int icc0 = s0 / 9, tap0 = s0 - icc0 * 9;
        int icc1 = s1 / 9, tap1 = s1 - icc1 * 9;
        const bf16* gA = w1bf + (size_t)p * 8192 + (size_t)selX * 4096 + cin8;
        #pragma unroll
        for (int i = 0; i < 4; i++)
            gload_lds16(gA + (i * 32 + r0) * 32,
                        &Abuf[(size_t)(i * 256 + wbase) * 8]);
        int tapS = selX ? tap1 : tap0;
        int iccS = selX ? icc1 : icc0;
        int posT = (row + tapS / 3) * HP_ + (tapS % 3);
        bool is8 = (iccS >= 8);
        const bf16* gb = is8 ? hb1 : (hb8 + (size_t)iccS * CHK);
        #pragma unroll
        for (int i = 0; i < 3; i++) {
            int c = i * 32 + r0;
            const bf16* g = is8 ? (gb + (size_t)(posT + c) * 8)
                                : (gb + (size_t)(posT + c) * 32 + cin8);
            gload_lds16(g, &Bbuf[(size_t)(i * 256 + wbase) * 8]);
        }
    };

    auto COMPUTE = [&]() {
        #pragma unroll
        for (int k = 0; k < 2; k++) {
            int swz = k ? swzE1 : swzE0;
            short8 a[4], bq[3];
            #pragma unroll
            for (int mt = 0; mt < 4; mt++)
                a[mt] = *reinterpret_cast<const short8*>(
                    &Abuf[(size_t)(wm * 64 + mt * 16 + l15) * 64 + swz]);
            #pragma unroll
            for (int nt = 0; nt < 3; nt++)
                bq[nt] = *reinterpret_cast<const short8*>(
                    &Bbuf[(size_t)(wn * 48 + nt * 16 + l15) * 64 + swz]);
            #pragma unroll
            for (int mt = 0; mt < 4; mt++)
                #pragma unroll
                for (int nt = 0; nt < 3; nt++)
                    acc[mt][nt] = __builtin_amdgcn_mfma_f32_16x16x32_bf16(
                        a[mt], bq[nt], acc[mt][nt], 0, 0, 0);
        }
    };

    for (int p = 0; p < 41; ++p) {
        STAGE(p);
        __syncthreads();
        COMPUTE();
        __syncthreads();
    }

    #pragma unroll
    for (int nt = 0; nt < 3; nt++) {
        int pxl = wn * 48 + nt * 16 + l15;
        #pragma unroll
        for (int mt = 0; mt < 4; mt++) {
            int ocb = wm * 64 + mt * 16 + lk * 4;
            float4 bias = *reinterpret_cast<const float4*>(b1 + ocb);
            const float* bp = reinterpret_cast<const float*>(&bias);
            ushort4 u;
            u.x = bfb(fmaxf(acc[mt][nt][0] + bp[0], 0.f));
            u.y = bfb(fmaxf(acc[mt][nt][1] + bp[1], 0.f));
            u.z = bfb(fmaxf(acc[mt][nt][2] + bp[2], 0.f));
            u.w = bfb(fmaxf(acc[mt][nt][3] + bp[3], 0.f));
            int chunk = (ocb >> 3) ^ (pxl & 7);
            *reinterpret_cast<ushort4*>(&S[(size_t)pxl * 128 + chunk * 8 + (lk & 1) * 4]) = u;
        }
    }
    __syncthreads();
    {
        bf16* dst = hmidp + (size_t)b * HPW * 128 + ((size_t)(row + 1) * HP_ + 1) * 128;
        #pragma unroll
        for (int i = 0; i < 6; i++) {
            int f = tid + i * 256;
            int px = f >> 4, cc = f & 15;
            short8 v = *reinterpret_cast<const short8*>(
                &S[(size_t)px * 128 + (cc ^ (px & 7)) * 8]);
            *reinterpret_cast<short8*>(dst + (size_t)f * 8) = v;
        }
    }
}

// ---------------------------------------------------------------- conv2 ----
__global__ __launch_bounds__(128)
void conv2_mfma(const bf16* __restrict__ hmidp, const bf16* __restrict__ w2bf,
                const float* __restrict__ b2, float* __restrict__ out)
{
    __shared__ bf16 Abuf[1024];
    __shared__ bf16 Bbuf[6144];
    int gid = blockIdx.x;             // 768 = 8 b x 96 rows
    int b = gid & 7;
    int y = gid >> 3;
    int p0 = y * 96;
    int tid = threadIdx.x, lane = tid & 63;
    int wn = tid >> 6;
    int l15 = lane & 15, lk = lane >> 4;
    const bf16* hb = hmidp + (size_t)b * HPW * 128;

    int wbase = tid & 64;
    int t3 = (tid >> 3) & 7;
    int cX = (tid & 7) ^ t3;
    int r0 = tid >> 3;
    int swzE0 = ((lk) ^ (l15 & 7)) * 8;
    int swzE1 = ((4 + lk) ^ (l15 & 7)) * 8;

    f32x4 acc[3] = {};

    auto STAGE = [&](int s) {
        int tap = s >> 1, half = s & 1;
        int toff = (tap / 3) * HP_ + (tap % 3);
        gload_lds16(w2bf + ((size_t)s * 16 + r0) * 64 + cX * 8,
                    &Abuf[(size_t)wbase * 8]);
        #pragma unroll
        for (int i = 0; i < 6; i++) {
            int c = i * 16 + r0;
            gload_lds16(hb + (size_t)(y * HP_ + c + toff) * 128 + half * 64 + cX * 8,
                        &Bbuf[(size_t)(i * 128 + wbase) * 8]);
        }
    };

    auto COMPUTE = [&]() {
        #pragma unroll
        for (int k = 0; k < 2; k++) {
            int swz = k ? swzE1 : swzE0;
            short8 a = *reinterpret_cast<const short8*>(&Abuf[(size_t)l15 * 64 + swz]);
            #pragma unroll
            for (int nt = 0; nt < 3; nt++) {
                short8 bq = *reinterpret_cast<const short8*>(
                    &Bbuf[(size_t)(wn * 48 + nt * 16 + l15) * 64 + swz]);
                acc[nt] = __builtin_amdgcn_mfma_f32_16x16x32_bf16(a, bq, acc[nt], 0, 0, 0);
            }
        }
    };

    for (int s = 0; s < 18; ++s) {
        STAGE(s);
        __syncthreads();
        COMPUTE();
        __syncthreads();
    }

    if (lk == 0) {
        float bb0 = b2[0], bb1 = b2[1];
        #pragma unroll
        for (int nt = 0; nt < 3; nt++) {
            int px = p0 + wn * 48 + nt * 16 + l15;
            out[((size_t)b * 2 + 0) * HW_ + px] = acc[nt][0] + bb0;
            out[((size_t)b * 2 + 1) * HW_ + px] = acc[nt][1] + bb1;
        }
    }
}

// ---------------------------------------------------------------- launch ----
extern "C" void kernel_launch(void* const* d_in, const int* in_sizes, int n_in,
                              void* d_out, int out_size, void* d_ws, size_t ws_size,
                              hipStream_t stream)
{
    const float* cur_embed  = (const float*)d_in[0];
    const float* cur_decode = (const float*)d_in[1];
    const float* init_embed = (const float*)d_in[2];
    const float* init_seg   = (const float*)d_in[3];
    const float* prev_embed = (const float*)d_in[4];
    const float* prev_seg   = (const float*)d_in[5];
    const float* W1 = (const float*)d_in[6];
    const float* b1 = (const float*)d_in[7];
    const float* W2 = (const float*)d_in[8];
    const float* b2 = (const float*)d_in[9];
    float* out = (float*)d_out;

    char* ws = (char*)d_ws;
    bf16* hcat8 = (bf16*)ws;
    bf16* curbf = (bf16*)ws;                          // alias (dead after lmap)
    bf16* hcat1 = (bf16*)(ws + 39337984);
    const size_t HCAT_REGION = 40567296;
    bf16* hmidp  = (bf16*)(ws + HCAT_REGION);
    bf16* fibf   = (bf16*)(ws + HCAT_REGION);
    bf16* prevbf = (bf16*)(ws + HCAT_REGION);
    float* si  = (float*)(ws + HCAT_REGION + 2621440);
    bf16* w1bf = (bf16*)(ws + 60236288);
    bf16* w2bf = (bf16*)(ws + 60908032);
    float* gout = (float*)(ws + 60944896);
    float* lout = (float*)(ws + 61534720);
    const bf16* zbuf = w1bf + (size_t)81 * 4096;      // slab 81 = zeros

    { prep_kernel<<<11152, 256, 0, stream>>>(W1, W2, init_embed, init_seg, cur_embed,
                                             w1bf, w2bf, fibf, si, curbf); }
    { gmap_mfma<<<768, 256, 0, stream>>>(curbf, fibf, si, gout); }
    for (int g = 0; g < 2; g++) {
        dim3 gt(144, 4, 4);
        tcur_kernel<<<gt, 256, 0, stream>>>(prev_embed + (size_t)g * 4 * C_ * HW_, prevbf);
        dim3 gl(144, 4);
        lmap_mfma<<<gl, 256, 0, stream>>>(curbf, prevbf, zbuf, prev_seg, lout, g * 4);
    }
    { packall_kernel<<<4909, 256, 0, stream>>>(cur_decode, gout, lout, init_seg,
                                               prev_seg, hcat8, hcat1, hmidp); }
    { conv1_mfma<<<768, 256, 0, stream>>>(hcat8, hcat1, w1bf, b1, hmidp); }
    { conv2_mfma<<<768, 128, 0, stream>>>(hmidp, w2bf, b2, out); }
}